// Round 10
// baseline (127.249 us; speedup 1.0000x reference)
//
#include <hip/hip_runtime.h>
#include <hip/hip_bf16.h>
#include <math.h>

#define BS   8
#define NPTS 2048
#define CCH  12      // channels per flow
#define NF   2       // flow dim
#define DIM  24      // NF*CCH, feats order: d = f*12 + c
#define KPAD 32      // MFMA K (24 + 8 zero pad)
#define KTOP 16
#define NWV  8       // waves per fused block (512 threads)
#define RPB  16      // rows per block (one m-tile)
#define CBUF 144     // survivor slots per row (~19 expected @ margin 1.6e-2, huge headroom)
#define CBS  145     // padded stride

#define NROWS    (BS * NPTS)
#define TGT_BASE (NROWS * KTOP * CCH)   // 3145728
#define SXC_PER_B (NPTS * KTOP * CCH)   // 393216 floats per batch in sx_c

// hi-only bf16 approx: |approx - exact| <= 2*2^-8 + accum ~ 7.9e-3; margin = 2*eps
#define MARGIN 0.016f

typedef unsigned long long u64;
typedef unsigned int       u32;
typedef unsigned short     u16;
typedef __attribute__((ext_vector_type(8))) short short8;   // bf16x8 MFMA frag
typedef __attribute__((ext_vector_type(4))) float f32x4;

// ws layout (bytes)
#define WS_FEATS 0                                  // fp32 [NROWS][24]
#define WS_RAW   (NROWS * DIM * 4)                  // fp32 [NROWS][12]
#define WS_FHI   (WS_RAW + NROWS * CCH * 4)         // bf16 [NROWS][32]

// Emulate np.linalg.norm(v) + 1e-8 in float32 exactly (numpy pairwise sum, n=24)
__device__ __forceinline__ float np_norm_den(const float* __restrict__ v)
{
#pragma clang fp contract(off)
    float s[DIM];
    #pragma unroll
    for (int d = 0; d < DIM; ++d) s[d] = v[d] * v[d];
    float r[8];
    #pragma unroll
    for (int j = 0; j < 8; ++j) r[j] = (s[j] + s[j + 8]) + s[j + 16];
    float res = ((r[0] + r[1]) + (r[2] + r[3])) + ((r[4] + r[5]) + (r[6] + r[7]));
    return sqrtf(res) + 1e-8f;
}

// Monotone float -> u32 (preserves total order for finite floats)
__device__ __forceinline__ u32 ordf(float f)
{
    u32 u = __float_as_uint(f);
    return ((int)u >= 0) ? (u | 0x80000000u) : ~u;
}

// round-to-nearest-even fp32 -> bf16 bits (finite inputs)
__device__ __forceinline__ u16 bf16_rne(float x)
{
    u32 bits = __float_as_uint(x);
    bits += 0x7fffu + ((bits >> 16) & 1u);
    return (u16)(bits >> 16);
}

// running top-4 insert (desc t0>=t1>=t2>=t3): 1 max + 3 med3
__device__ __forceinline__ void ins4(float& t0, float& t1, float& t2, float& t3, float v)
{
#if __has_builtin(__builtin_amdgcn_fmed3f)
    const float n0 = fmaxf(t0, v);
    const float n1 = __builtin_amdgcn_fmed3f(t0, t1, v);
    const float n2 = __builtin_amdgcn_fmed3f(t1, t2, v);
    const float n3 = __builtin_amdgcn_fmed3f(t2, t3, v);
#else
    const float n0 = fmaxf(t0, v);
    const float n1 = fmaxf(t1, fminf(t0, v));
    const float n2 = fmaxf(t2, fminf(t1, v));
    const float n3 = fmaxf(t3, fminf(t2, v));
#endif
    t0 = n0; t1 = n1; t2 = n2; t3 = n3;
}

#define CE(a, b) { const float h_ = fmaxf(a, b), l_ = fminf(a, b); a = h_; b = l_; }

// ---------------------------------------------------------------------------
// R23: SINGLE KERNEL with per-batch SOFTWARE barrier (R9's cooperative
// launch was rejected by graph capture -> kernel never ran).
//  * Each block preps its own 16 rows (tid<16, chain byte-identical to the
//    old prep_kernel), then all 128 blocks of batch b sync on an XCD-local
//    atomic counter before the scan phase reads batch-b fhi/feats/raw.
//  * Barrier cell = out_u32[b*SXC_PER_B]: harness memsets out to 0 before
//    every launch (guaranteed-zero counter); the cell is only overwritten
//    by chunk-0's gather, a full fused-body (~30us) AFTER that block passed
//    the barrier; even the overwritten float bits compare >=128 unsigned
//    (any non-denormal float >= 0x00800000), so late polls can't mis-read.
//  * Deadlock safety: grid 1024 = exactly 4 blocks/CU x 256 CU;
//    __launch_bounds__(512,8) forces VGPR<=64 -> full-grid residency
//    guaranteed (LDS 4x~20KB << 160KB).  Natural VGPR was 40-48 (R2-R8),
//    so the 64-cap should not spill the main loop.
//  * R21 pinning (b = bid&7) keeps producer+consumer+barrier on XCD b:
//    no cross-XCD coherence exposure (kernel-begin acquire invalidates
//    stale poison lines; prep writes and scan reads share XCD-b L2).
// R16/R17/R21: swapped-operand hi-only MFMA scan, top-4/wave + exact
// 16th-of-32 threshold, depth-2 prefetch, XCD batch pinning, exact fp32
// rescue + rank-select + gather.
// ---------------------------------------------------------------------------
__global__ __launch_bounds__(512, 8) void mega_kernel(
    const float* __restrict__ x_c,     // [8][12][2][2048]
    const int*   __restrict__ flow_p,
    float*       __restrict__ feats,   // [NROWS][24] normalized fp32
    u16*         __restrict__ fhi,     // [NROWS][32] bf16 hi
    float*       __restrict__ raw,     // [NROWS][12] raw flow slice
    float*       __restrict__ out)
{
    __shared__ union {
        f32x4 vk4[NWV * 16];          // 2 KiB: per-wave top-4 lists [w][row16]
        u64   ckey[RPB * CBS];        // 18.1 KiB: survivors (disjoint in time)
    } sh;
    __shared__ float thr_s[RPB];
    __shared__ int   cnt[RPB];
    __shared__ int   sel[RPB][KTOP];

    const int tid  = threadIdx.x;
    const int lane = tid & 63;
    const int w    = __builtin_amdgcn_readfirstlane(tid >> 6);  // 0..7
    const int b     = (int)(blockIdx.x & 7);     // batch -> XCD b (R21)
    const int chunk = (int)(blockIdx.x >> 3);    // 0..127
    const int rb    = chunk * RPB;           // row base within batch
    const int p     = lane & 15;             // our row (C-col with swapped ops)
    const int q     = lane >> 4;             // cand quad (C-row group)

    // ================= PREP PHASE: this block's 16 rows ====================
    if (tid < RPB) {
        const int n = rb + tid;                 // row within batch
        const int t = b * NPTS + n;             // global row
        const float* xb = x_c + (size_t)b * CCH * NF * NPTS;

        float v[DIM];
        float fn[DIM];
        {
#pragma clang fp contract(off)
            #pragma unroll
            for (int c = 0; c < CCH; ++c)
                #pragma unroll
                for (int f = 0; f < NF; ++f)
                    v[f * CCH + c] = xb[(c * NF + f) * NPTS + n];

            const float den = np_norm_den(v);
            #pragma unroll
            for (int d = 0; d < DIM; ++d) fn[d] = v[d] / den;
        }

        float* fo = feats + (size_t)t * DIM;
        #pragma unroll
        for (int j = 0; j < 6; ++j)
            *(f32x4*)(fo + 4 * j) = *(f32x4*)(fn + 4 * j);

        u16 hb[KPAD];
        #pragma unroll
        for (int d = 0; d < DIM; ++d) hb[d] = bf16_rne(fn[d]);
        #pragma unroll
        for (int d = DIM; d < KPAD; ++d) hb[d] = 0;

        u16* ho = fhi + (size_t)t * KPAD;
        #pragma unroll
        for (int j = 0; j < 4; ++j)
            *(short8*)(ho + 8 * j) = ((const short8*)hb)[j];

        const int flow = flow_p[0];
        float rv[CCH];
        #pragma unroll
        for (int c = 0; c < CCH; ++c) {
            rv[c] = flow ? v[CCH + c] : v[c];
            out[TGT_BASE + ((size_t)b * CCH + c) * NPTS + n] = rv[c];
        }
        float* ro = raw + (size_t)t * CCH;
        #pragma unroll
        for (int j = 0; j < 3; ++j)
            *(f32x4*)(ro + 4 * j) = *(f32x4*)(rv + 4 * j);
    }

    // ================= PER-BATCH BARRIER (128 blocks, XCD-local) ==========
    {
        u32* bar = (u32*)out + (size_t)b * SXC_PER_B;   // zeroed by harness
        __syncthreads();                 // block's prep stores issued
        if (tid == 0) {
            __threadfence();             // prep stores visible (device scope)
            atomicAdd(bar, 1u);
            u32 v;
            do {
                v = __hip_atomic_load(bar, __ATOMIC_ACQUIRE,
                                      __HIP_MEMORY_SCOPE_AGENT);
                if (v < 128u) __builtin_amdgcn_s_sleep(2);
            } while (v < 128u);
        }
        __syncthreads();                 // whole block released
    }

    // ================= FUSED BODY (unchanged from R8) ======================
    if (tid < RPB) cnt[tid] = 0;

    // row fragment (B-operand under swap): rows rb+p, k = q*8..q*8+7
    short8 arow;
    {
        const u32 ae = (u32)((b * NPTS + rb + p) * KPAD + q * 8);
        arow = *(const short8*)(fhi + ae);
    }

    // ---- Pass 1: wave w scans cands [w*128, +128) (8 tiles), running top-4
    //      per (row p, cand-slice q); 2 interleaved lists + depth-2 prefetch.
    float ta0 = -3.0f, ta1 = -3.0f, ta2 = -3.0f, ta3 = -3.0f;
    float tb0 = -3.0f, tb1 = -3.0f, tb2 = -3.0f, tb3 = -3.0f;
    {
        const u32 base1 = (u32)((b * NPTS + w * 128 + p) * KPAD + q * 8);
        short8 pA = *(const short8*)(fhi + base1);          // tile t
        short8 pB = *(const short8*)(fhi + base1 + 512);    // tile t+1
        #pragma unroll
        for (int t = 0; t < 8; t += 2) {
            const short8 c0 = pA;
            if (t + 2 < 8) pA = *(const short8*)(fhi + base1 + (u32)(t + 2) * 512);
            f32x4 acc0 = {0.0f, 0.0f, 0.0f, 0.0f};
            acc0 = __builtin_amdgcn_mfma_f32_16x16x32_bf16(c0, arow, acc0, 0, 0, 0);
            const short8 c1 = pB;
            if (t + 3 < 8) pB = *(const short8*)(fhi + base1 + (u32)(t + 3) * 512);
            f32x4 acc1 = {0.0f, 0.0f, 0.0f, 0.0f};
            acc1 = __builtin_amdgcn_mfma_f32_16x16x32_bf16(c1, arow, acc1, 0, 0, 0);
            #pragma unroll
            for (int i = 0; i < 4; ++i) ins4(ta0, ta1, ta2, ta3, acc0[i]);
            #pragma unroll
            for (int i = 0; i < 4; ++i) ins4(tb0, tb1, tb2, tb3, acc1[i]);
        }
    }
    // merge the two interleaved lists -> top-4 (bitonic: max(a_i, b_{3-i}) + cleanup)
    float t0 = fmaxf(ta0, tb3), t1 = fmaxf(ta1, tb2), t2 = fmaxf(ta2, tb1), t3 = fmaxf(ta3, tb0);
    CE(t0, t2) CE(t1, t3) CE(t0, t1) CE(t2, t3)

    // ---- unify the 4 q-copies of each row (shfl merges) ----
    #pragma unroll
    for (int x = 16; x <= 32; x <<= 1) {
        const float o0 = __shfl_xor(t0, x), o1 = __shfl_xor(t1, x);
        const float o2 = __shfl_xor(t2, x), o3 = __shfl_xor(t3, x);
        float m0 = fmaxf(t0, o3), m1 = fmaxf(t1, o2), m2 = fmaxf(t2, o1), m3 = fmaxf(t3, o0);
        CE(m0, m2) CE(m1, m3) CE(m0, m1) CE(m2, m3)
        t0 = m0; t1 = m1; t2 = m2; t3 = m3;
    }

    // ---- publish per-wave top-4 per row ----
    if (q == 0) {
        f32x4 v4 = {t0, t1, t2, t3};
        sh.vk4[w * 16 + p] = v4;
    }
    __syncthreads();

    // ---- wave 0: exact 16th of the 32 collected values per row ----
    if (w == 0) {
        const int j = q;                       // 0..3
        const f32x4 A  = sh.vk4[j * 16 + p];
        const f32x4 Bv = sh.vk4[(j + 4) * 16 + p];
        // merge two sorted-4 desc -> sorted-8 desc
        float s0 = fmaxf(A[0], Bv[3]), s1 = fmaxf(A[1], Bv[2]);
        float s2 = fmaxf(A[2], Bv[1]), s3 = fmaxf(A[3], Bv[0]);
        float s4 = fminf(A[0], Bv[3]), s5 = fminf(A[1], Bv[2]);
        float s6 = fminf(A[2], Bv[1]), s7 = fminf(A[3], Bv[0]);
        CE(s0, s2) CE(s1, s3) CE(s0, s1) CE(s2, s3)
        CE(s4, s6) CE(s5, s7) CE(s4, s5) CE(s6, s7)
        float s[8] = {s0, s1, s2, s3, s4, s5, s6, s7};
        // j ^ 1 merge: two sorted-8 -> sorted-16 desc
        float t16[16];
        {
            float o[8];
            #pragma unroll
            for (int i = 0; i < 8; ++i) o[i] = __shfl_xor(s[i], 16);
            #pragma unroll
            for (int i = 0; i < 8; ++i) {
                t16[i]     = fmaxf(s[i], o[7 - i]);
                t16[8 + i] = fminf(s[i], o[7 - i]);
            }
            #pragma unroll
            for (int base = 0; base < 16; base += 8) {
                CE(t16[base + 0], t16[base + 4]) CE(t16[base + 1], t16[base + 5])
                CE(t16[base + 2], t16[base + 6]) CE(t16[base + 3], t16[base + 7])
                CE(t16[base + 0], t16[base + 2]) CE(t16[base + 1], t16[base + 3])
                CE(t16[base + 4], t16[base + 6]) CE(t16[base + 5], t16[base + 7])
                CE(t16[base + 0], t16[base + 1]) CE(t16[base + 2], t16[base + 3])
                CE(t16[base + 4], t16[base + 5]) CE(t16[base + 6], t16[base + 7])
            }
        }
        // j ^ 2 final: 16th of union = min_i max(mine[i], other[15-i])
        float z[16];
        #pragma unroll
        for (int i = 0; i < 16; ++i)
            z[i] = fmaxf(t16[i], __shfl_xor(t16[15 - i], 32));
        float mn = z[0];
        #pragma unroll
        for (int i = 1; i < 16; ++i) mn = fminf(mn, z[i]);
        if (q == 0) thr_s[p] = mn - MARGIN;    // lb - 2*eps
    }
    __syncthreads();                 // thr ready; vk4 dead -> ckey usable

    const float thrp = thr_s[p];     // this lane's row threshold

    // ---- Pass 2: all 2048 cands (wave w: [w*256,+256)), depth-2 prefetch ----
    {
        const u32 base2 = (u32)((b * NPTS + w * 256 + p) * KPAD + q * 8);
        short8 pA = *(const short8*)(fhi + base2);
        short8 pB = *(const short8*)(fhi + base2 + 512);
        #pragma unroll
        for (int t = 0; t < 16; t += 2) {
            const short8 c0 = pA;
            if (t + 2 < 16) pA = *(const short8*)(fhi + base2 + (u32)(t + 2) * 512);
            f32x4 acc0 = {0.0f, 0.0f, 0.0f, 0.0f};
            acc0 = __builtin_amdgcn_mfma_f32_16x16x32_bf16(c0, arow, acc0, 0, 0, 0);
            const short8 c1 = pB;
            if (t + 3 < 16) pB = *(const short8*)(fhi + base2 + (u32)(t + 3) * 512);
            f32x4 acc1 = {0.0f, 0.0f, 0.0f, 0.0f};
            acc1 = __builtin_amdgcn_mfma_f32_16x16x32_bf16(c1, arow, acc1, 0, 0, 0);
            const int cb0 = w * 256 + t * 16;
            // early-out: skip the 4 compare-branches when no value hits
            const float mx0 = fmaxf(fmaxf(acc0[0], acc0[1]), fmaxf(acc0[2], acc0[3]));
            if (mx0 >= thrp) {
                #pragma unroll
                for (int i = 0; i < 4; ++i) {
                    if (acc0[i] >= thrp) {
                        const int pos = atomicAdd(&cnt[p], 1);
                        if (pos < CBUF)
                            sh.ckey[p * CBS + pos] = (u64)(u32)(cb0 + q * 4 + i);
                    }
                }
            }
            const float mx1 = fmaxf(fmaxf(acc1[0], acc1[1]), fmaxf(acc1[2], acc1[3]));
            if (mx1 >= thrp) {
                #pragma unroll
                for (int i = 0; i < 4; ++i) {
                    if (acc1[i] >= thrp) {
                        const int pos = atomicAdd(&cnt[p], 1);
                        if (pos < CBUF)
                            sh.ckey[p * CBS + pos] = (u64)(u32)(cb0 + 16 + q * 4 + i);
                    }
                }
            }
        }
    }
    __syncthreads();

    // ---- exact rescue: bit-exact fp32 chain on survivors only ----
    {
        const int r = tid & 15;                  // row within chunk
        const float* fr = feats + (u32)((b * NPTS + rb + r) * DIM);
        float rfn[DIM];
        #pragma unroll
        for (int j = 0; j < 6; ++j)
            *(f32x4*)(rfn + 4 * j) = *(const f32x4*)(fr + 4 * j);
        const int e = (cnt[r] < CBUF) ? cnt[r] : CBUF;
        for (int pos = tid >> 4; pos < e; pos += 32) {
            const int idx = (int)(u32)sh.ckey[r * CBS + pos];
            const float* cp = feats + (u32)((b * NPTS + idx) * DIM);
            float cv[DIM];
            #pragma unroll
            for (int j = 0; j < 6; ++j)
                *(f32x4*)(cv + 4 * j) = *(const f32x4*)(cp + 4 * j);
            float acc = 0.0f;
            #pragma unroll
            for (int d = 0; d < DIM; ++d)
                acc = __builtin_fmaf(cv[d], rfn[d], acc);   // exact chain
            sh.ckey[r * CBS + pos] = ((u64)ordf(acc) << 32) | (u32)(2047 - idx);
        }
    }
    __syncthreads();

    // ---- parallel rank-select: 32 threads per row ----
    {
        const int L = tid >> 5;                  // 0..15
        const int g = tid & 31;
        const int e = (cnt[L] < CBUF) ? cnt[L] : CBUF;
        const u64* rowbuf = &sh.ckey[L * CBS];
        for (int pos = g; pos < e; pos += 32) {
            const u64 key = rowbuf[pos];
            int rank = 0;
            for (int p2 = 0; p2 < e; ++p2) rank += (rowbuf[p2] > key);
            if (rank < KTOP) sel[L][rank] = 2047 - (int)(key & 0xFFFFFFFFull);
        }
    }
    __syncthreads();

    // ---- gather: sx_c[b, n, k, c] = raw[(b*2048 + sel)*12 + c] ----
    // div-free row mapping (L = tid>>5, 32 threads/row, 6 elems each)
    {
        const int rg = b * NPTS + rb;
        const int L = tid >> 5;                  // 0..15
        const int g = tid & 31;
        #pragma unroll
        for (int j = 0; j < 6; ++j) {
            const int e3 = g + j * 32;           // 0..191
            const int k = e3 / CCH;
            const int c = e3 - k * CCH;
            out[((size_t)(rg + L) * KTOP + k) * CCH + c] =
                raw[(u32)((b * NPTS + sel[L][k]) * CCH) + c];
        }
    }
}

// ---------------------------------------------------------------------------
extern "C" void kernel_launch(void* const* d_in, const int* in_sizes, int n_in,
                              void* d_out, int out_size, void* d_ws, size_t ws_size,
                              hipStream_t stream)
{
    const float* x_c    = (const float*)d_in[0];
    const int*   flow_p = (const int*)d_in[1];
    float*       out    = (float*)d_out;

    float* feats = (float*)((char*)d_ws + WS_FEATS);
    float* raw   = (float*)((char*)d_ws + WS_RAW);
    u16*   fhi   = (u16*)  ((char*)d_ws + WS_FHI);

    mega_kernel<<<BS * 128, 512, 0, stream>>>(x_c, flow_p, feats, fhi, raw, out);
}

// Round 11
// 90.989 us; speedup vs baseline: 1.3985x; 1.3985x over previous
//
#include <hip/hip_runtime.h>
#include <hip/hip_bf16.h>
#include <math.h>

#define BS   8
#define NPTS 2048
#define CCH  12      // channels per flow
#define NF   2       // flow dim
#define DIM  24      // NF*CCH, feats order: d = f*12 + c
#define KPAD 32      // MFMA K (24 + 8 zero pad)
#define KTOP 16
#define NWV  8       // waves per fused block (512 threads)
#define RPB  16      // rows per block (one m-tile)
#define CBUF 144     // survivor slots per row (~19 expected @ margin 1.6e-2, huge headroom)
#define CBS  145     // padded stride

#define NROWS    (BS * NPTS)
#define TGT_BASE (NROWS * KTOP * CCH)   // 3145728

// hi-only bf16 approx: |approx - exact| <= 2*2^-8 + accum ~ 7.9e-3; margin = 2*eps
#define MARGIN 0.016f

typedef unsigned long long u64;
typedef unsigned int       u32;
typedef unsigned short     u16;
typedef __attribute__((ext_vector_type(8))) short short8;   // bf16x8 MFMA frag
typedef __attribute__((ext_vector_type(4))) float f32x4;

// ws layout (bytes)
#define WS_FEATS 0                                  // fp32 [NROWS][24]
#define WS_RAW   (NROWS * DIM * 4)                  // fp32 [NROWS][12]
#define WS_FHI   (WS_RAW + NROWS * CCH * 4)         // bf16 [NROWS][32]

// ---------------------------------------------------------------------------
// R24 = exact revert to R8 (best passing: 90.0 us).
// Journal of closed avenues (do NOT retry):
//  * R14/R23: __launch_bounds__ occupancy caps (x,6)/(x,8) -> allocator
//    squeezed 20+ regs below natural -> spills; -5 to -40 us regressions.
//  * R18/R19: retained pass-1 dots in regs -> +16 VGPR crossed the 64-reg
//    8-wave/SIMD cliff; +4.5 us.  (Also: inline-asm v_cvt_pk_bf16_f32
//    half-order caused silent index/value decoupling -> absmax 7.3.)
//  * R20: cohort s_sleep stagger -> null (lockstep theory dead).
//  * R22: hipLaunchCooperativeKernel -> rejected under graph capture
//    (kernel never ran, output all zeros).
//  * R23: software per-batch barrier -> barrier + 16/512-thread prep phase
//    + VGPR crush = 77-85 us mega kernel; -37 us total regression.
// Confirmed wins retained here:
//  * R16: swapped-operand MFMA (row lane-local, no LDS transpose), hi-only
//    scan, top-4/wave + exact-16th-of-32 threshold, exact fp32 rescue.
//  * R17: u32 offsets + depth-2 prefetch (neutral-to-slightly-positive).
//  * R21: XCD batch pinning b=bid&7 (-2.6 us, L2-resident scans).
// ---------------------------------------------------------------------------

// Emulate np.linalg.norm(v) + 1e-8 in float32 exactly (numpy pairwise sum, n=24)
__device__ __forceinline__ float np_norm_den(const float* __restrict__ v)
{
#pragma clang fp contract(off)
    float s[DIM];
    #pragma unroll
    for (int d = 0; d < DIM; ++d) s[d] = v[d] * v[d];
    float r[8];
    #pragma unroll
    for (int j = 0; j < 8; ++j) r[j] = (s[j] + s[j + 8]) + s[j + 16];
    float res = ((r[0] + r[1]) + (r[2] + r[3])) + ((r[4] + r[5]) + (r[6] + r[7]));
    return sqrtf(res) + 1e-8f;
}

// Monotone float -> u32 (preserves total order for finite floats)
__device__ __forceinline__ u32 ordf(float f)
{
    u32 u = __float_as_uint(f);
    return ((int)u >= 0) ? (u | 0x80000000u) : ~u;
}

// round-to-nearest-even fp32 -> bf16 bits (finite inputs)
__device__ __forceinline__ u16 bf16_rne(float x)
{
    u32 bits = __float_as_uint(x);
    bits += 0x7fffu + ((bits >> 16) & 1u);
    return (u16)(bits >> 16);
}

// running top-4 insert (desc t0>=t1>=t2>=t3): 1 max + 3 med3
__device__ __forceinline__ void ins4(float& t0, float& t1, float& t2, float& t3, float v)
{
#if __has_builtin(__builtin_amdgcn_fmed3f)
    const float n0 = fmaxf(t0, v);
    const float n1 = __builtin_amdgcn_fmed3f(t0, t1, v);
    const float n2 = __builtin_amdgcn_fmed3f(t1, t2, v);
    const float n3 = __builtin_amdgcn_fmed3f(t2, t3, v);
#else
    const float n0 = fmaxf(t0, v);
    const float n1 = fmaxf(t1, fminf(t0, v));
    const float n2 = fmaxf(t2, fminf(t1, v));
    const float n3 = fmaxf(t3, fminf(t2, v));
#endif
    t0 = n0; t1 = n1; t2 = n2; t3 = n3;
}

#define CE(a, b) { const float h_ = fmaxf(a, b), l_ = fminf(a, b); a = h_; b = l_; }

// ---------------------------------------------------------------------------
// Kernel 0: normalize rows (numpy-exact fp32); write fp32 feats, bf16 hi
// (K-padded to 32), raw flow slice, and the tgt_out output.
// R21: XCD-pinned indexing — block i handles batch (i&7), row-segment
// (i>>3): all blocks of batch b land on XCD b, so writes stay in the XCD
// whose fused blocks will consume them.
// ---------------------------------------------------------------------------
__global__ __launch_bounds__(64) void prep_kernel(
    const float* __restrict__ x_c,     // [8][12][2][2048]
    const int*   __restrict__ flow_p,
    float*       __restrict__ feats,   // [NROWS][24] normalized fp32
    u16*         __restrict__ fhi,     // [NROWS][32] bf16 hi
    float*       __restrict__ raw,     // [NROWS][12] raw flow slice
    float*       __restrict__ out)
{
    const int b   = (int)(blockIdx.x & 7);          // batch -> XCD b
    const int seg = (int)(blockIdx.x >> 3);         // 0..31
    const int n   = seg * 64 + threadIdx.x;         // row within batch
    const int t   = b * NPTS + n;                   // global row
    const float* xb = x_c + (size_t)b * CCH * NF * NPTS;

    float v[DIM];
    float fn[DIM];
    {
#pragma clang fp contract(off)
        #pragma unroll
        for (int c = 0; c < CCH; ++c)
            #pragma unroll
            for (int f = 0; f < NF; ++f)
                v[f * CCH + c] = xb[(c * NF + f) * NPTS + n];

        const float den = np_norm_den(v);
        #pragma unroll
        for (int d = 0; d < DIM; ++d) fn[d] = v[d] / den;
    }

    // vectorized feats store: 6 x f32x4
    float* fo = feats + (size_t)t * DIM;
    #pragma unroll
    for (int j = 0; j < 6; ++j)
        *(f32x4*)(fo + 4 * j) = *(f32x4*)(fn + 4 * j);

    // bf16 hi row in regs, store as 4 x short8
    u16 hb[KPAD];
    #pragma unroll
    for (int d = 0; d < DIM; ++d) hb[d] = bf16_rne(fn[d]);
    #pragma unroll
    for (int d = DIM; d < KPAD; ++d) hb[d] = 0;

    u16* ho = fhi + (size_t)t * KPAD;
    #pragma unroll
    for (int j = 0; j < 4; ++j)
        *(short8*)(ho + 8 * j) = ((const short8*)hb)[j];

    const int flow = flow_p[0];
    float rv[CCH];
    #pragma unroll
    for (int c = 0; c < CCH; ++c) {
        rv[c] = flow ? v[CCH + c] : v[c];
        out[TGT_BASE + ((size_t)b * CCH + c) * NPTS + n] = rv[c];
    }
    float* ro = raw + (size_t)t * CCH;
    #pragma unroll
    for (int j = 0; j < 3; ++j)
        *(f32x4*)(ro + 4 * j) = *(f32x4*)(rv + 4 * j);
}

// ---------------------------------------------------------------------------
// Fused kernel: block = (batch, 16-row chunk), 512 thr = 8 waves, 1024 blocks.
// ---------------------------------------------------------------------------
__global__ __launch_bounds__(512) void fused_topk_kernel(
    const float* __restrict__ feats,
    const u16*   __restrict__ fhi,
    const float* __restrict__ raw,
    float*       __restrict__ out)
{
    __shared__ union {
        f32x4 vk4[NWV * 16];          // 2 KiB: per-wave top-4 lists [w][row16]
        u64   ckey[RPB * CBS];        // 18.1 KiB: survivors (disjoint in time)
    } sh;
    __shared__ float thr_s[RPB];
    __shared__ int   cnt[RPB];
    __shared__ int   sel[RPB][KTOP];

    const int tid  = threadIdx.x;
    const int lane = tid & 63;
    const int w    = __builtin_amdgcn_readfirstlane(tid >> 6);  // 0..7
    const int b     = (int)(blockIdx.x & 7);     // batch -> XCD b (R21)
    const int chunk = (int)(blockIdx.x >> 3);    // 0..127
    const int rb    = chunk * RPB;           // row base within batch
    const int p     = lane & 15;             // our row (C-col with swapped ops)
    const int q     = lane >> 4;             // cand quad (C-row group)

    if (tid < RPB) cnt[tid] = 0;

    // row fragment (B-operand under swap): rows rb+p, k = q*8..q*8+7
    short8 arow;
    {
        const u32 ae = (u32)((b * NPTS + rb + p) * KPAD + q * 8);
        arow = *(const short8*)(fhi + ae);
    }

    // ---- Pass 1: wave w scans cands [w*128, +128) (8 tiles), running top-4
    //      per (row p, cand-slice q); 2 interleaved lists + depth-2 prefetch.
    float ta0 = -3.0f, ta1 = -3.0f, ta2 = -3.0f, ta3 = -3.0f;
    float tb0 = -3.0f, tb1 = -3.0f, tb2 = -3.0f, tb3 = -3.0f;
    {
        const u32 base1 = (u32)((b * NPTS + w * 128 + p) * KPAD + q * 8);
        short8 pA = *(const short8*)(fhi + base1);          // tile t
        short8 pB = *(const short8*)(fhi + base1 + 512);    // tile t+1
        #pragma unroll
        for (int t = 0; t < 8; t += 2) {
            const short8 c0 = pA;
            if (t + 2 < 8) pA = *(const short8*)(fhi + base1 + (u32)(t + 2) * 512);
            f32x4 acc0 = {0.0f, 0.0f, 0.0f, 0.0f};
            acc0 = __builtin_amdgcn_mfma_f32_16x16x32_bf16(c0, arow, acc0, 0, 0, 0);
            const short8 c1 = pB;
            if (t + 3 < 8) pB = *(const short8*)(fhi + base1 + (u32)(t + 3) * 512);
            f32x4 acc1 = {0.0f, 0.0f, 0.0f, 0.0f};
            acc1 = __builtin_amdgcn_mfma_f32_16x16x32_bf16(c1, arow, acc1, 0, 0, 0);
            #pragma unroll
            for (int i = 0; i < 4; ++i) ins4(ta0, ta1, ta2, ta3, acc0[i]);
            #pragma unroll
            for (int i = 0; i < 4; ++i) ins4(tb0, tb1, tb2, tb3, acc1[i]);
        }
    }
    // merge the two interleaved lists -> top-4 (bitonic: max(a_i, b_{3-i}) + cleanup)
    float t0 = fmaxf(ta0, tb3), t1 = fmaxf(ta1, tb2), t2 = fmaxf(ta2, tb1), t3 = fmaxf(ta3, tb0);
    CE(t0, t2) CE(t1, t3) CE(t0, t1) CE(t2, t3)

    // ---- unify the 4 q-copies of each row (shfl merges) ----
    #pragma unroll
    for (int x = 16; x <= 32; x <<= 1) {
        const float o0 = __shfl_xor(t0, x), o1 = __shfl_xor(t1, x);
        const float o2 = __shfl_xor(t2, x), o3 = __shfl_xor(t3, x);
        float m0 = fmaxf(t0, o3), m1 = fmaxf(t1, o2), m2 = fmaxf(t2, o1), m3 = fmaxf(t3, o0);
        CE(m0, m2) CE(m1, m3) CE(m0, m1) CE(m2, m3)
        t0 = m0; t1 = m1; t2 = m2; t3 = m3;
    }

    // ---- publish per-wave top-4 per row ----
    if (q == 0) {
        f32x4 v4 = {t0, t1, t2, t3};
        sh.vk4[w * 16 + p] = v4;
    }
    __syncthreads();

    // ---- wave 0: exact 16th of the 32 collected values per row ----
    if (w == 0) {
        const int j = q;                       // 0..3
        const f32x4 A  = sh.vk4[j * 16 + p];
        const f32x4 Bv = sh.vk4[(j + 4) * 16 + p];
        // merge two sorted-4 desc -> sorted-8 desc
        float s0 = fmaxf(A[0], Bv[3]), s1 = fmaxf(A[1], Bv[2]);
        float s2 = fmaxf(A[2], Bv[1]), s3 = fmaxf(A[3], Bv[0]);
        float s4 = fminf(A[0], Bv[3]), s5 = fminf(A[1], Bv[2]);
        float s6 = fminf(A[2], Bv[1]), s7 = fminf(A[3], Bv[0]);
        CE(s0, s2) CE(s1, s3) CE(s0, s1) CE(s2, s3)
        CE(s4, s6) CE(s5, s7) CE(s4, s5) CE(s6, s7)
        float s[8] = {s0, s1, s2, s3, s4, s5, s6, s7};
        // j ^ 1 merge: two sorted-8 -> sorted-16 desc
        float t16[16];
        {
            float o[8];
            #pragma unroll
            for (int i = 0; i < 8; ++i) o[i] = __shfl_xor(s[i], 16);
            #pragma unroll
            for (int i = 0; i < 8; ++i) {
                t16[i]     = fmaxf(s[i], o[7 - i]);
                t16[8 + i] = fminf(s[i], o[7 - i]);
            }
            #pragma unroll
            for (int base = 0; base < 16; base += 8) {
                CE(t16[base + 0], t16[base + 4]) CE(t16[base + 1], t16[base + 5])
                CE(t16[base + 2], t16[base + 6]) CE(t16[base + 3], t16[base + 7])
                CE(t16[base + 0], t16[base + 2]) CE(t16[base + 1], t16[base + 3])
                CE(t16[base + 4], t16[base + 6]) CE(t16[base + 5], t16[base + 7])
                CE(t16[base + 0], t16[base + 1]) CE(t16[base + 2], t16[base + 3])
                CE(t16[base + 4], t16[base + 5]) CE(t16[base + 6], t16[base + 7])
            }
        }
        // j ^ 2 final: 16th of union = min_i max(mine[i], other[15-i])
        float z[16];
        #pragma unroll
        for (int i = 0; i < 16; ++i)
            z[i] = fmaxf(t16[i], __shfl_xor(t16[15 - i], 32));
        float mn = z[0];
        #pragma unroll
        for (int i = 1; i < 16; ++i) mn = fminf(mn, z[i]);
        if (q == 0) thr_s[p] = mn - MARGIN;    // lb - 2*eps
    }
    __syncthreads();                 // thr ready; vk4 dead -> ckey usable

    const float thrp = thr_s[p];     // this lane's row threshold

    // ---- Pass 2: all 2048 cands (wave w: [w*256,+256)), depth-2 prefetch ----
    {
        const u32 base2 = (u32)((b * NPTS + w * 256 + p) * KPAD + q * 8);
        short8 pA = *(const short8*)(fhi + base2);
        short8 pB = *(const short8*)(fhi + base2 + 512);
        #pragma unroll
        for (int t = 0; t < 16; t += 2) {
            const short8 c0 = pA;
            if (t + 2 < 16) pA = *(const short8*)(fhi + base2 + (u32)(t + 2) * 512);
            f32x4 acc0 = {0.0f, 0.0f, 0.0f, 0.0f};
            acc0 = __builtin_amdgcn_mfma_f32_16x16x32_bf16(c0, arow, acc0, 0, 0, 0);
            const short8 c1 = pB;
            if (t + 3 < 16) pB = *(const short8*)(fhi + base2 + (u32)(t + 3) * 512);
            f32x4 acc1 = {0.0f, 0.0f, 0.0f, 0.0f};
            acc1 = __builtin_amdgcn_mfma_f32_16x16x32_bf16(c1, arow, acc1, 0, 0, 0);
            const int cb0 = w * 256 + t * 16;
            // early-out: skip the 4 compare-branches when no value hits
            const float mx0 = fmaxf(fmaxf(acc0[0], acc0[1]), fmaxf(acc0[2], acc0[3]));
            if (mx0 >= thrp) {
                #pragma unroll
                for (int i = 0; i < 4; ++i) {
                    if (acc0[i] >= thrp) {
                        const int pos = atomicAdd(&cnt[p], 1);
                        if (pos < CBUF)
                            sh.ckey[p * CBS + pos] = (u64)(u32)(cb0 + q * 4 + i);
                    }
                }
            }
            const float mx1 = fmaxf(fmaxf(acc1[0], acc1[1]), fmaxf(acc1[2], acc1[3]));
            if (mx1 >= thrp) {
                #pragma unroll
                for (int i = 0; i < 4; ++i) {
                    if (acc1[i] >= thrp) {
                        const int pos = atomicAdd(&cnt[p], 1);
                        if (pos < CBUF)
                            sh.ckey[p * CBS + pos] = (u64)(u32)(cb0 + 16 + q * 4 + i);
                    }
                }
            }
        }
    }
    __syncthreads();

    // ---- exact rescue: bit-exact fp32 chain on survivors only ----
    {
        const int r = tid & 15;                  // row within chunk
        const float* fr = feats + (u32)((b * NPTS + rb + r) * DIM);
        float rfn[DIM];
        #pragma unroll
        for (int j = 0; j < 6; ++j)
            *(f32x4*)(rfn + 4 * j) = *(const f32x4*)(fr + 4 * j);
        const int e = (cnt[r] < CBUF) ? cnt[r] : CBUF;
        for (int pos = tid >> 4; pos < e; pos += 32) {
            const int idx = (int)(u32)sh.ckey[r * CBS + pos];
            const float* cp = feats + (u32)((b * NPTS + idx) * DIM);
            float cv[DIM];
            #pragma unroll
            for (int j = 0; j < 6; ++j)
                *(f32x4*)(cv + 4 * j) = *(const f32x4*)(cp + 4 * j);
            float acc = 0.0f;
            #pragma unroll
            for (int d = 0; d < DIM; ++d)
                acc = __builtin_fmaf(cv[d], rfn[d], acc);   // exact chain
            sh.ckey[r * CBS + pos] = ((u64)ordf(acc) << 32) | (u32)(2047 - idx);
        }
    }
    __syncthreads();

    // ---- parallel rank-select: 32 threads per row ----
    {
        const int L = tid >> 5;                  // 0..15
        const int g = tid & 31;
        const int e = (cnt[L] < CBUF) ? cnt[L] : CBUF;
        const u64* rowbuf = &sh.ckey[L * CBS];
        for (int pos = g; pos < e; pos += 32) {
            const u64 key = rowbuf[pos];
            int rank = 0;
            for (int p2 = 0; p2 < e; ++p2) rank += (rowbuf[p2] > key);
            if (rank < KTOP) sel[L][rank] = 2047 - (int)(key & 0xFFFFFFFFull);
        }
    }
    __syncthreads();

    // ---- gather: sx_c[b, n, k, c] = raw[(b*2048 + sel)*12 + c] ----
    // div-free row mapping (L = tid>>5, 32 threads/row, 6 elems each)
    {
        const int rg = b * NPTS + rb;
        const int L = tid >> 5;                  // 0..15
        const int g = tid & 31;
        #pragma unroll
        for (int j = 0; j < 6; ++j) {
            const int e3 = g + j * 32;           // 0..191
            const int k = e3 / CCH;
            const int c = e3 - k * CCH;
            out[((size_t)(rg + L) * KTOP + k) * CCH + c] =
                raw[(u32)((b * NPTS + sel[L][k]) * CCH) + c];
        }
    }
}

// ---------------------------------------------------------------------------
extern "C" void kernel_launch(void* const* d_in, const int* in_sizes, int n_in,
                              void* d_out, int out_size, void* d_ws, size_t ws_size,
                              hipStream_t stream)
{
    const float* x_c    = (const float*)d_in[0];
    const int*   flow_p = (const int*)d_in[1];
    float*       out    = (float*)d_out;

    float* feats = (float*)((char*)d_ws + WS_FEATS);
    float* raw   = (float*)((char*)d_ws + WS_RAW);
    u16*   fhi   = (u16*)  ((char*)d_ws + WS_FHI);

    prep_kernel<<<NROWS / 64, 64, 0, stream>>>(x_c, flow_p, feats, fhi, raw, out);
    fused_topk_kernel<<<BS * 128, 512, 0, stream>>>(feats, fhi, raw, out);
}